// Round 1
// baseline (626.127 us; speedup 1.0000x reference)
//
#include <hip/hip_runtime.h>
#include <math.h>

#define B_   4
#define C_   192
#define N_   6400
#define K_   9
#define M_   50
#define TK_  12
#define OC_  192
#define KC_  576     // 3*C
#define CH_  100     // n-chunks for centroid update (64 points each)
#define PT_  16      // points per logits block
#define SCS  193     // padded LDS row stride for centroid rows (conflict-free)

// ---------------- W re-permute: Wg[o][t*192+ch] = conv_w[o][ch*3+t] ----------
__global__ void k_rearrange_w(const float* __restrict__ cw, float* __restrict__ Wg) {
    int g = blockIdx.x * 256 + threadIdx.x;           // < 192*576
    int o = g / KC_, r = g % KC_;
    int t = r / C_, ch = r % C_;
    Wg[g] = cw[o * KC_ + ch * 3 + t];
}

// ---------------- transpose x (b,c,n) -> xt (b,n,c) --------------------------
__global__ void k_transpose(const float* __restrict__ x, float* __restrict__ xt) {
    __shared__ float tile[32][33];
    int b = blockIdx.z;
    int p0 = blockIdx.x * 32, c0 = blockIdx.y * 32;
    int tx = threadIdx.x, ty = threadIdx.y;
    const float* xb = x + (size_t)b * C_ * N_;
    float* xtb = xt + (size_t)b * N_ * C_;
#pragma unroll
    for (int i = 0; i < 4; i++) {
        int cc = ty + 8 * i;
        tile[cc][tx] = xb[(size_t)(c0 + cc) * N_ + p0 + tx];
    }
    __syncthreads();
#pragma unroll
    for (int i = 0; i < 4; i++) {
        int pp = ty + 8 * i;
        xtb[(size_t)(p0 + pp) * C_ + c0 + tx] = tile[tx][pp];
    }
}

// ---------------- initial centroids: 5x10 adaptive avg pool ------------------
__global__ void k_init_cent(const float* __restrict__ xt, float* __restrict__ cent) {
    int m = blockIdx.x, b = blockIdx.y, c = threadIdx.x;
    int gy = m / 10, gx = m % 10;
    const float* xtb = xt + (size_t)b * N_ * C_;
    float s = 0.f;
    for (int yy = 0; yy < 16; yy++)
        for (int xx = 0; xx < 8; xx++) {
            int p = (gy * 16 + yy) * 80 + gx * 8 + xx;
            s += xtb[(size_t)p * C_ + c];
        }
    cent[((size_t)b * M_ + m) * C_ + c] = s * (1.f / 128.f);
}

// ---------------- logits + softmax (+ topk on last iter) ---------------------
__global__ __launch_bounds__(256) void k_logits(const float* __restrict__ xt,
        const float* __restrict__ cent, float* __restrict__ w,
        int* __restrict__ nn, int do_topk) {
    __shared__ float sc[M_ * SCS];     // centroids, padded rows
    __shared__ float sp[PT_ * SCS];    // points, padded rows
    __shared__ float lg[PT_ * M_];
    __shared__ float c2p[200];
    __shared__ float c2[M_];
    __shared__ float ssum[PT_];
    int b = blockIdx.y;
    int p0 = blockIdx.x * PT_;
    int tid = threadIdx.x;
    const float* cb = cent + (size_t)b * M_ * C_;
    for (int j = tid; j < M_ * C_; j += 256) {
        int m = j / C_, kk = j % C_;
        sc[m * SCS + kk] = cb[j];
    }
    const float* xb = xt + ((size_t)b * N_ + p0) * C_;
    for (int j = tid; j < PT_ * C_; j += 256) {
        int p = j / C_, kk = j % C_;
        sp[p * SCS + kk] = xb[j];
    }
    __syncthreads();
    // c2[m] = |cent_m|^2, parallel over 200 threads (4 partials per m)
    if (tid < 200) {
        int m = tid >> 2, q = tid & 3;
        float s = 0.f;
        for (int kk = q * 48; kk < q * 48 + 48; kk++) {
            float v = sc[m * SCS + kk];
            s += v * v;
        }
        c2p[tid] = s;
    }
    __syncthreads();
    if (tid < M_) c2[tid] = c2p[tid * 4] + c2p[tid * 4 + 1] + c2p[tid * 4 + 2] + c2p[tid * 4 + 3];
    __syncthreads();
    // logits (softmax-equivalent): 2*dot - c2   (p2 shift dropped: uniform per row)
    for (int t = tid; t < PT_ * M_; t += 256) {
        int p = t & (PT_ - 1), m = t >> 4;
        const float* cr = &sc[m * SCS];
        const float* pr = &sp[p * SCS];
        float d = 0.f;
#pragma unroll 8
        for (int kk = 0; kk < C_; kk++) d += cr[kk] * pr[kk];
        lg[p * M_ + m] = 2.f * d - c2[m];
    }
    __syncthreads();
    if (tid < PT_) {
        int p = tid;
        float mx = -1e30f;
        for (int m = 0; m < M_; m++) mx = fmaxf(mx, lg[p * M_ + m]);
        float s = 0.f;
        for (int m = 0; m < M_; m++) {
            float e = expf(lg[p * M_ + m] - mx);
            lg[p * M_ + m] = e;
            s += e;
        }
        ssum[p] = s;
    }
    __syncthreads();
    float* wb = w + ((size_t)b * N_ + p0) * M_;
    for (int j = tid; j < PT_ * M_; j += 256) {
        int p = j / M_;
        wb[j] = lg[j] / ssum[p];
    }
    __syncthreads();
    if (do_topk && tid < PT_) {
        int p = tid;
        int* nb = nn + ((size_t)b * N_ + p0 + p) * TK_;
        for (int r = 0; r < TK_; r++) {
            float bv = -1.f;
            int bi = 0;
            for (int m = 0; m < M_; m++) {
                float v = lg[p * M_ + m];
                if (v > bv) { bv = v; bi = m; }   // strict > : lowest index wins ties
            }
            nb[r] = bi;
            lg[p * M_ + bi] = -1.f;
        }
    }
}

// ---------------- centroid update: per-chunk partial sums --------------------
__global__ __launch_bounds__(192) void k_upd_partial(const float* __restrict__ xt,
        const float* __restrict__ w, float* __restrict__ part, float* __restrict__ wsp) {
    __shared__ float wl[64 * M_];
    int ch = blockIdx.x, b = blockIdx.y, c = threadIdx.x;
    int p0 = ch * 64;
    const float* wb = w + ((size_t)b * N_ + p0) * M_;
    for (int j = c; j < 64 * M_; j += 192) wl[j] = wb[j];
    __syncthreads();
    float acc[M_];
#pragma unroll
    for (int m = 0; m < M_; m++) acc[m] = 0.f;
    const float* xb = xt + ((size_t)b * N_ + p0) * C_;
    for (int p = 0; p < 64; p++) {
        float xv = xb[(size_t)p * C_ + c];
        const float* wr = &wl[p * M_];
#pragma unroll
        for (int m = 0; m < M_; m++) acc[m] += wr[m] * xv;   // LDS broadcast reads
    }
    float* pb = part + ((size_t)b * CH_ + ch) * (size_t)(M_ * C_);
#pragma unroll
    for (int m = 0; m < M_; m++) pb[(size_t)m * C_ + c] = acc[m];
    if (c < M_) {
        float s = 0.f;
        for (int p = 0; p < 64; p++) s += wl[p * M_ + c];
        wsp[((size_t)b * CH_ + ch) * M_ + c] = s;
    }
}

__global__ __launch_bounds__(192) void k_upd_reduce(const float* __restrict__ part,
        const float* __restrict__ wsp, float* __restrict__ cent) {
    int m = blockIdx.x, b = blockIdx.y, c = threadIdx.x;
    __shared__ float sws;
    if (c == 0) {
        float s = 0.f;
        for (int ch = 0; ch < CH_; ch++) s += wsp[((size_t)b * CH_ + ch) * M_ + m];
        sws = s + 1e-8f;
    }
    float s = 0.f;
    for (int ch = 0; ch < CH_; ch++)
        s += part[((size_t)b * CH_ + ch) * (size_t)(M_ * C_) + (size_t)m * C_ + c];
    __syncthreads();
    cent[((size_t)b * M_ + m) * C_ + c] = s / sws;
}

// ---------------- gathers: edge max-relative + topk-centroid max -------------
__global__ __launch_bounds__(192) void k_gather(const float* __restrict__ xt,
        const float* __restrict__ cent, const int* __restrict__ edge,
        const int* __restrict__ nn, float* __restrict__ xjt, float* __restrict__ xjct) {
    __shared__ int sidx[2 * K_ + TK_];
    int p = blockIdx.x, b = blockIdx.y, c = threadIdx.x;
    if (c < K_)
        sidx[c] = edge[((size_t)b * N_ + p) * K_ + c];                               // j from e[0]
    else if (c < 2 * K_)
        sidx[c] = edge[(size_t)B_ * N_ * K_ + ((size_t)b * N_ + p) * K_ + (c - K_)]; // i from e[1]
    else if (c < 2 * K_ + TK_)
        sidx[c] = nn[((size_t)b * N_ + p) * TK_ + (c - 2 * K_)];
    __syncthreads();
    const float* xb = xt + (size_t)b * N_ * C_;
    const float* cbv = cent + (size_t)b * M_ * C_;
    float xv = xb[(size_t)p * C_ + c];
    float mj = -1e30f;
#pragma unroll
    for (int kk = 0; kk < K_; kk++) {
        float vj = xb[(size_t)sidx[kk] * C_ + c];
        float vi = xb[(size_t)sidx[K_ + kk] * C_ + c];
        mj = fmaxf(mj, vj - vi);
    }
    float mc = -1e30f;
#pragma unroll
    for (int kk = 0; kk < TK_; kk++)
        mc = fmaxf(mc, cbv[(size_t)sidx[2 * K_ + kk] * C_ + c]);
    size_t o = ((size_t)b * N_ + p) * C_ + c;
    xjt[o] = mj;
    xjct[o] = mc - xv;
}

// ---------------- final conv: out[b][o][p] = relu(Wg . feat_p + bias) --------
__global__ __launch_bounds__(256) void k_gemm(const float* __restrict__ Wg,
        const float* __restrict__ xt, const float* __restrict__ xjt,
        const float* __restrict__ xjct, const float* __restrict__ bias,
        float* __restrict__ out) {
    __shared__ float As[16][68];   // As[kk][o_local]
    __shared__ float Bs[16][68];   // Bs[kk][p_local]
    int b = blockIdx.z;
    int po = blockIdx.x * 64, oo = blockIdx.y * 64;
    int tid = threadIdx.x;
    int tx = tid & 15, ty = tid >> 4;
    float acc[4][4];
#pragma unroll
    for (int i = 0; i < 4; i++)
#pragma unroll
        for (int j = 0; j < 4; j++) acc[i][j] = 0.f;
    int lr = tid >> 2;   // 0..63
    int lq = tid & 3;    // 0..3
    const float* s0 = xt + (size_t)b * N_ * C_;
    const float* s1 = xjt + (size_t)b * N_ * C_;
    const float* s2 = xjct + (size_t)b * N_ * C_;
    for (int kt = 0; kt < 36; kt++) {
        int kg = kt * 16;
        int prt = kg / C_, koff = kg % C_;
        const float* src = (prt == 0) ? s0 : ((prt == 1) ? s1 : s2);
        float4 wv = *(const float4*)&Wg[(size_t)(oo + lr) * KC_ + kg + 4 * lq];
        float4 bv = *(const float4*)&src[(size_t)(po + lr) * C_ + koff + 4 * lq];
        __syncthreads();
        As[4 * lq + 0][lr] = wv.x; As[4 * lq + 1][lr] = wv.y;
        As[4 * lq + 2][lr] = wv.z; As[4 * lq + 3][lr] = wv.w;
        Bs[4 * lq + 0][lr] = bv.x; Bs[4 * lq + 1][lr] = bv.y;
        Bs[4 * lq + 2][lr] = bv.z; Bs[4 * lq + 3][lr] = bv.w;
        __syncthreads();
#pragma unroll
        for (int kk = 0; kk < 16; kk++) {
            float4 a = *(const float4*)&As[kk][4 * ty];
            float4 bb = *(const float4*)&Bs[kk][4 * tx];
            acc[0][0] += a.x * bb.x; acc[0][1] += a.x * bb.y; acc[0][2] += a.x * bb.z; acc[0][3] += a.x * bb.w;
            acc[1][0] += a.y * bb.x; acc[1][1] += a.y * bb.y; acc[1][2] += a.y * bb.z; acc[1][3] += a.y * bb.w;
            acc[2][0] += a.z * bb.x; acc[2][1] += a.z * bb.y; acc[2][2] += a.z * bb.z; acc[2][3] += a.z * bb.w;
            acc[3][0] += a.w * bb.x; acc[3][1] += a.w * bb.y; acc[3][2] += a.w * bb.z; acc[3][3] += a.w * bb.w;
        }
    }
#pragma unroll
    for (int i = 0; i < 4; i++) {
        int o = oo + 4 * ty + i;
        float bi = bias[o];
        float4 r;
        r.x = fmaxf(acc[i][0] + bi, 0.f);
        r.y = fmaxf(acc[i][1] + bi, 0.f);
        r.z = fmaxf(acc[i][2] + bi, 0.f);
        r.w = fmaxf(acc[i][3] + bi, 0.f);
        *(float4*)&out[((size_t)b * OC_ + o) * N_ + po + 4 * tx] = r;
    }
}

extern "C" void kernel_launch(void* const* d_in, const int* in_sizes, int n_in,
                              void* d_out, int out_size, void* d_ws, size_t ws_size,
                              hipStream_t stream) {
    (void)in_sizes; (void)n_in; (void)out_size; (void)ws_size;
    const float* x   = (const float*)d_in[0];
    const int* edge  = (const int*)d_in[1];
    const float* cw  = (const float*)d_in[2];
    const float* cbi = (const float*)d_in[3];
    float* ws = (float*)d_ws;
    size_t o = 0;
    float* xt   = ws + o; o += (size_t)B_ * N_ * C_;     // 4,915,200
    float* Wg   = ws + o; o += (size_t)OC_ * KC_;        // 110,592
    float* cent = ws + o; o += (size_t)B_ * M_ * C_;     // 38,400
    float* w    = ws + o; o += (size_t)B_ * N_ * M_;     // 1,280,000
    float* part = ws + o; o += (size_t)B_ * CH_ * M_ * C_; // 3,840,000
    float* wsp  = ws + o; o += (size_t)B_ * CH_ * M_;    // 20,000
    int* nn = (int*)(ws + o); o += (size_t)B_ * N_ * TK_; // 307,200
    float* xjt  = ws + o; o += (size_t)B_ * N_ * C_;
    float* xjct = ws + o; o += (size_t)B_ * N_ * C_;
    float* outp = (float*)d_out;

    k_rearrange_w<<<dim3(432), dim3(256), 0, stream>>>(cw, Wg);
    k_transpose<<<dim3(N_ / 32, C_ / 32, B_), dim3(32, 8), 0, stream>>>(x, xt);
    k_init_cent<<<dim3(M_, B_), dim3(192), 0, stream>>>(xt, cent);
    for (int it = 0; it < 3; it++) {
        k_logits<<<dim3(N_ / PT_, B_), dim3(256), 0, stream>>>(xt, cent, w, nn, (it == 2) ? 1 : 0);
        k_upd_partial<<<dim3(CH_, B_), dim3(192), 0, stream>>>(xt, w, part, wsp);
        k_upd_reduce<<<dim3(M_, B_), dim3(192), 0, stream>>>(part, wsp, cent);
    }
    k_gather<<<dim3(N_, B_), dim3(192), 0, stream>>>(xt, cent, edge, nn, xjt, xjct);
    k_gemm<<<dim3(N_ / 64, OC_ / 64, B_), dim3(256), 0, stream>>>(Wg, xt, xjt, xjct, cbi, outp);
}

// Round 2
// 400.556 us; speedup vs baseline: 1.5631x; 1.5631x over previous
//
#include <hip/hip_runtime.h>
#include <math.h>

#define B_   4
#define C_   192
#define N_   6400
#define K_   9
#define M_   50
#define TK_  12
#define OC_  192
#define KC_  576     // 3*C
#define CH_  100     // n-chunks for centroid update (64 points each)
#define MS_  25      // m-slice per upd_partial block
#define LSTR 53      // padded lg row stride (53 mod 32 = 21, coprime -> conflict-free)

// ---------------- W re-permute: Wg[o][t*192+ch] = conv_w[o][ch*3+t] ----------
__global__ void k_rearrange_w(const float* __restrict__ cw, float* __restrict__ Wg) {
    int g = blockIdx.x * 256 + threadIdx.x;           // < 192*576
    int o = g / KC_, r = g % KC_;
    int t = r / C_, ch = r % C_;
    Wg[g] = cw[o * KC_ + ch * 3 + t];
}

// ---------------- transpose x (b,c,n) -> xt (b,n,c) --------------------------
__global__ void k_transpose(const float* __restrict__ x, float* __restrict__ xt) {
    __shared__ float tile[32][33];
    int b = blockIdx.z;
    int p0 = blockIdx.x * 32, c0 = blockIdx.y * 32;
    int tx = threadIdx.x, ty = threadIdx.y;
    const float* xb = x + (size_t)b * C_ * N_;
    float* xtb = xt + (size_t)b * N_ * C_;
#pragma unroll
    for (int i = 0; i < 4; i++) {
        int cc = ty + 8 * i;
        tile[cc][tx] = xb[(size_t)(c0 + cc) * N_ + p0 + tx];
    }
    __syncthreads();
#pragma unroll
    for (int i = 0; i < 4; i++) {
        int pp = ty + 8 * i;
        xtb[(size_t)(p0 + pp) * C_ + c0 + tx] = tile[tx][pp];
    }
}

// ---------------- initial centroids: 5x10 adaptive avg pool (+ |c|^2) --------
__global__ __launch_bounds__(192) void k_init_cent(const float* __restrict__ xt,
        float* __restrict__ cent, float* __restrict__ c2) {
    int m = blockIdx.x, b = blockIdx.y, c = threadIdx.x;
    int gy = m / 10, gx = m % 10;
    const float* xtb = xt + (size_t)b * N_ * C_;
    float s = 0.f;
    for (int yy = 0; yy < 16; yy++)
        for (int xx = 0; xx < 8; xx++) {
            int p = (gy * 16 + yy) * 80 + gx * 8 + xx;
            s += xtb[(size_t)p * C_ + c];
        }
    float v = s * (1.f / 128.f);
    cent[((size_t)b * M_ + m) * C_ + c] = v;
    float q = v * v;
    __shared__ float red[3];
#pragma unroll
    for (int off = 32; off > 0; off >>= 1) q += __shfl_down(q, off, 64);
    if ((c & 63) == 0) red[c >> 6] = q;
    __syncthreads();
    if (c == 0) c2[(size_t)b * M_ + m] = red[0] + red[1] + red[2];
}

// ---------------- logits GEMM + softmax (+ topk on last iter) ----------------
// tile: 64 points x 64 m (50 valid), K=192 in chunks of 16
__global__ __launch_bounds__(256) void k_logits(const float* __restrict__ xt,
        const float* __restrict__ cent, const float* __restrict__ c2g,
        float* __restrict__ w, int* __restrict__ nn, int do_topk) {
    __shared__ float Ac[16][68];    // centroids: Ac[kk][m]
    __shared__ float Bp[16][68];    // points:    Bp[kk][p]
    __shared__ float lg[64 * LSTR];
    int b = blockIdx.y;
    int p0 = blockIdx.x * 64;
    int tid = threadIdx.x;
    int tx = tid & 15, ty = tid >> 4;
    int lr = tid >> 2, lq = tid & 3;
    const float* cb = cent + (size_t)b * M_ * C_;
    const float* xb = xt + ((size_t)b * N_ + p0) * C_;
    float acc[4][4];
#pragma unroll
    for (int i = 0; i < 4; i++)
#pragma unroll
        for (int j = 0; j < 4; j++) acc[i][j] = 0.f;
    for (int kt = 0; kt < 12; kt++) {
        int kg = kt * 16;
        float4 cv = make_float4(0.f, 0.f, 0.f, 0.f);
        if (lr < M_) cv = *(const float4*)&cb[(size_t)lr * C_ + kg + 4 * lq];
        float4 pv = *(const float4*)&xb[(size_t)lr * C_ + kg + 4 * lq];
        __syncthreads();
        Ac[4 * lq + 0][lr] = cv.x; Ac[4 * lq + 1][lr] = cv.y;
        Ac[4 * lq + 2][lr] = cv.z; Ac[4 * lq + 3][lr] = cv.w;
        Bp[4 * lq + 0][lr] = pv.x; Bp[4 * lq + 1][lr] = pv.y;
        Bp[4 * lq + 2][lr] = pv.z; Bp[4 * lq + 3][lr] = pv.w;
        __syncthreads();
#pragma unroll
        for (int kk = 0; kk < 16; kk++) {
            float4 a = *(const float4*)&Ac[kk][4 * ty];
            float4 bb = *(const float4*)&Bp[kk][4 * tx];
            acc[0][0] += a.x * bb.x; acc[0][1] += a.x * bb.y; acc[0][2] += a.x * bb.z; acc[0][3] += a.x * bb.w;
            acc[1][0] += a.y * bb.x; acc[1][1] += a.y * bb.y; acc[1][2] += a.y * bb.z; acc[1][3] += a.y * bb.w;
            acc[2][0] += a.z * bb.x; acc[2][1] += a.z * bb.y; acc[2][2] += a.z * bb.z; acc[2][3] += a.z * bb.w;
            acc[3][0] += a.w * bb.x; acc[3][1] += a.w * bb.y; acc[3][2] += a.w * bb.z; acc[3][3] += a.w * bb.w;
        }
    }
    // epilogue: lg[p][m] = 2*dot - |c_m|^2   (p2 shift dropped: softmax/topk invariant)
    float c2v[4];
#pragma unroll
    for (int i = 0; i < 4; i++) {
        int m = 4 * ty + i;
        c2v[i] = (m < M_) ? c2g[(size_t)b * M_ + m] : 0.f;
    }
#pragma unroll
    for (int i = 0; i < 4; i++) {
        int m = 4 * ty + i;
        if (m < M_) {
#pragma unroll
            for (int j = 0; j < 4; j++)
                lg[(4 * tx + j) * LSTR + m] = 2.f * acc[i][j] - c2v[i];
        }
    }
    __syncthreads();
    if (tid < 64) {
        float* row = &lg[tid * LSTR];
        float mx = -1e30f;
        for (int m = 0; m < M_; m++) mx = fmaxf(mx, row[m]);
        float s = 0.f;
        for (int m = 0; m < M_; m++) {
            float e = expf(row[m] - mx);
            row[m] = e;
            s += e;
        }
        float inv = 1.f / s;
        for (int m = 0; m < M_; m++) row[m] *= inv;
    }
    __syncthreads();
    float* wb = w + ((size_t)b * N_ + p0) * M_;
    for (int j = tid; j < 64 * M_; j += 256) {
        int p = j / M_, m = j - p * M_;
        wb[j] = lg[p * LSTR + m];
    }
    if (do_topk) {
        __syncthreads();
        if (tid < 64) {
            float* row = &lg[tid * LSTR];
            int* nb = nn + ((size_t)b * N_ + p0 + tid) * TK_;
            for (int r = 0; r < TK_; r++) {
                float bv = -1.f;
                int bi = 0;
                for (int m = 0; m < M_; m++) {
                    float v = row[m];
                    if (v > bv) { bv = v; bi = m; }   // strict > : lowest index wins ties
                }
                nb[r] = bi;
                row[bi] = -1.f;
            }
        }
    }
}

// ---------------- centroid update: per-chunk, per-m-slice partial sums -------
__global__ __launch_bounds__(192) void k_upd_partial(const float* __restrict__ xt,
        const float* __restrict__ w, float* __restrict__ part, float* __restrict__ wsp) {
    __shared__ float wl[64 * MS_];
    int ch = blockIdx.x, mh = blockIdx.y, b = blockIdx.z, c = threadIdx.x;
    int m0 = mh * MS_;
    int p0 = ch * 64;
    const float* wb = w + ((size_t)b * N_ + p0) * M_;
    for (int j = c; j < 64 * MS_; j += 192) {
        int p = j / MS_, mm = j - p * MS_;
        wl[j] = wb[p * M_ + m0 + mm];
    }
    __syncthreads();
    float acc[MS_];
#pragma unroll
    for (int mm = 0; mm < MS_; mm++) acc[mm] = 0.f;
    const float* xb = xt + ((size_t)b * N_ + p0) * C_;
    for (int p = 0; p < 64; p++) {
        float xv = xb[(size_t)p * C_ + c];
        const float* wr = &wl[p * MS_];
#pragma unroll
        for (int mm = 0; mm < MS_; mm++) acc[mm] += wr[mm] * xv;   // LDS broadcast reads
    }
    float* pb = part + (((size_t)b * CH_ + ch) * M_ + m0) * (size_t)C_;
#pragma unroll
    for (int mm = 0; mm < MS_; mm++) pb[(size_t)mm * C_ + c] = acc[mm];
    if (c < MS_) {
        float s = 0.f;
        for (int p = 0; p < 64; p++) s += wl[p * MS_ + c];
        wsp[((size_t)b * CH_ + ch) * M_ + m0 + c] = s;
    }
}

__global__ __launch_bounds__(192) void k_upd_reduce(const float* __restrict__ part,
        const float* __restrict__ wsp, float* __restrict__ cent, float* __restrict__ c2) {
    int m = blockIdx.x, b = blockIdx.y, c = threadIdx.x;
    __shared__ float sws;
    __shared__ float red[3];
    if (c == 0) {
        float s = 0.f;
        for (int ch = 0; ch < CH_; ch++) s += wsp[((size_t)b * CH_ + ch) * M_ + m];
        sws = s + 1e-8f;
    }
    float s = 0.f;
    for (int ch = 0; ch < CH_; ch++)
        s += part[(((size_t)b * CH_ + ch) * M_ + m) * (size_t)C_ + c];
    __syncthreads();
    float v = s / sws;
    cent[((size_t)b * M_ + m) * C_ + c] = v;
    float q = v * v;
#pragma unroll
    for (int off = 32; off > 0; off >>= 1) q += __shfl_down(q, off, 64);
    if ((c & 63) == 0) red[c >> 6] = q;
    __syncthreads();
    if (c == 0) c2[(size_t)b * M_ + m] = red[0] + red[1] + red[2];
}

// ---------------- gathers: edge max-relative + topk-centroid max -------------
__global__ __launch_bounds__(192) void k_gather(const float* __restrict__ xt,
        const float* __restrict__ cent, const int* __restrict__ edge,
        const int* __restrict__ nn, float* __restrict__ xjt, float* __restrict__ xjct) {
    __shared__ int sidx[2 * K_ + TK_];
    int p = blockIdx.x, b = blockIdx.y, c = threadIdx.x;
    if (c < K_)
        sidx[c] = edge[((size_t)b * N_ + p) * K_ + c];                               // j from e[0]
    else if (c < 2 * K_)
        sidx[c] = edge[(size_t)B_ * N_ * K_ + ((size_t)b * N_ + p) * K_ + (c - K_)]; // i from e[1]
    else if (c < 2 * K_ + TK_)
        sidx[c] = nn[((size_t)b * N_ + p) * TK_ + (c - 2 * K_)];
    __syncthreads();
    const float* xb = xt + (size_t)b * N_ * C_;
    const float* cbv = cent + (size_t)b * M_ * C_;
    float xv = xb[(size_t)p * C_ + c];
    float mj = -1e30f;
#pragma unroll
    for (int kk = 0; kk < K_; kk++) {
        float vj = xb[(size_t)sidx[kk] * C_ + c];
        float vi = xb[(size_t)sidx[K_ + kk] * C_ + c];
        mj = fmaxf(mj, vj - vi);
    }
    float mc = -1e30f;
#pragma unroll
    for (int kk = 0; kk < TK_; kk++)
        mc = fmaxf(mc, cbv[(size_t)sidx[2 * K_ + kk] * C_ + c]);
    size_t o = ((size_t)b * N_ + p) * C_ + c;
    xjt[o] = mj;
    xjct[o] = mc - xv;
}

// ---------------- final conv: out[b][o][p] = relu(Wg . feat_p + bias) --------
__global__ __launch_bounds__(256) void k_gemm(const float* __restrict__ Wg,
        const float* __restrict__ xt, const float* __restrict__ xjt,
        const float* __restrict__ xjct, const float* __restrict__ bias,
        float* __restrict__ out) {
    __shared__ float As[16][68];   // As[kk][o_local]
    __shared__ float Bs[16][68];   // Bs[kk][p_local]
    int b = blockIdx.z;
    int po = blockIdx.x * 64, oo = blockIdx.y * 64;
    int tid = threadIdx.x;
    int tx = tid & 15, ty = tid >> 4;
    float acc[4][4];
#pragma unroll
    for (int i = 0; i < 4; i++)
#pragma unroll
        for (int j = 0; j < 4; j++) acc[i][j] = 0.f;
    int lr = tid >> 2;   // 0..63
    int lq = tid & 3;    // 0..3
    const float* s0 = xt + (size_t)b * N_ * C_;
    const float* s1 = xjt + (size_t)b * N_ * C_;
    const float* s2 = xjct + (size_t)b * N_ * C_;
    for (int kt = 0; kt < 36; kt++) {
        int kg = kt * 16;
        int prt = kg / C_, koff = kg % C_;
        const float* src = (prt == 0) ? s0 : ((prt == 1) ? s1 : s2);
        float4 wv = *(const float4*)&Wg[(size_t)(oo + lr) * KC_ + kg + 4 * lq];
        float4 bv = *(const float4*)&src[(size_t)(po + lr) * C_ + koff + 4 * lq];
        __syncthreads();
        As[4 * lq + 0][lr] = wv.x; As[4 * lq + 1][lr] = wv.y;
        As[4 * lq + 2][lr] = wv.z; As[4 * lq + 3][lr] = wv.w;
        Bs[4 * lq + 0][lr] = bv.x; Bs[4 * lq + 1][lr] = bv.y;
        Bs[4 * lq + 2][lr] = bv.z; Bs[4 * lq + 3][lr] = bv.w;
        __syncthreads();
#pragma unroll
        for (int kk = 0; kk < 16; kk++) {
            float4 a = *(const float4*)&As[kk][4 * ty];
            float4 bb = *(const float4*)&Bs[kk][4 * tx];
            acc[0][0] += a.x * bb.x; acc[0][1] += a.x * bb.y; acc[0][2] += a.x * bb.z; acc[0][3] += a.x * bb.w;
            acc[1][0] += a.y * bb.x; acc[1][1] += a.y * bb.y; acc[1][2] += a.y * bb.z; acc[1][3] += a.y * bb.w;
            acc[2][0] += a.z * bb.x; acc[2][1] += a.z * bb.y; acc[2][2] += a.z * bb.z; acc[2][3] += a.z * bb.w;
            acc[3][0] += a.w * bb.x; acc[3][1] += a.w * bb.y; acc[3][2] += a.w * bb.z; acc[3][3] += a.w * bb.w;
        }
    }
#pragma unroll
    for (int i = 0; i < 4; i++) {
        int o = oo + 4 * ty + i;
        float bi = bias[o];
        float4 r;
        r.x = fmaxf(acc[i][0] + bi, 0.f);
        r.y = fmaxf(acc[i][1] + bi, 0.f);
        r.z = fmaxf(acc[i][2] + bi, 0.f);
        r.w = fmaxf(acc[i][3] + bi, 0.f);
        *(float4*)&out[((size_t)b * OC_ + o) * N_ + po + 4 * tx] = r;
    }
}

extern "C" void kernel_launch(void* const* d_in, const int* in_sizes, int n_in,
                              void* d_out, int out_size, void* d_ws, size_t ws_size,
                              hipStream_t stream) {
    (void)in_sizes; (void)n_in; (void)out_size; (void)ws_size;
    const float* x   = (const float*)d_in[0];
    const int* edge  = (const int*)d_in[1];
    const float* cw  = (const float*)d_in[2];
    const float* cbi = (const float*)d_in[3];
    float* ws = (float*)d_ws;
    size_t o = 0;
    float* xt   = ws + o; o += (size_t)B_ * N_ * C_;       // 4,915,200
    float* Wg   = ws + o; o += (size_t)OC_ * KC_;          // 110,592
    float* cent = ws + o; o += (size_t)B_ * M_ * C_;       // 38,400
    float* c2   = ws + o; o += (size_t)B_ * M_;            // 200
    float* w    = ws + o; o += (size_t)B_ * N_ * M_;       // 1,280,000
    float* part = ws + o; o += (size_t)B_ * CH_ * M_ * C_; // 3,840,000
    float* wsp  = ws + o; o += (size_t)B_ * CH_ * M_;      // 20,000
    int* nn = (int*)(ws + o); o += (size_t)B_ * N_ * TK_;  // 307,200
    float* xjt  = ws + o; o += (size_t)B_ * N_ * C_;
    float* xjct = ws + o; o += (size_t)B_ * N_ * C_;
    float* outp = (float*)d_out;

    k_rearrange_w<<<dim3(432), dim3(256), 0, stream>>>(cw, Wg);
    k_transpose<<<dim3(N_ / 32, C_ / 32, B_), dim3(32, 8), 0, stream>>>(x, xt);
    k_init_cent<<<dim3(M_, B_), dim3(192), 0, stream>>>(xt, cent, c2);
    for (int it = 0; it < 3; it++) {
        k_logits<<<dim3(N_ / 64, B_), dim3(256), 0, stream>>>(xt, cent, c2, w, nn, (it == 2) ? 1 : 0);
        k_upd_partial<<<dim3(CH_, 2, B_), dim3(192), 0, stream>>>(xt, w, part, wsp);
        k_upd_reduce<<<dim3(M_, B_), dim3(192), 0, stream>>>(part, wsp, cent, c2);
    }
    k_gather<<<dim3(N_, B_), dim3(192), 0, stream>>>(xt, cent, edge, nn, xjt, xjct);
    k_gemm<<<dim3(N_ / 64, OC_ / 64, B_), dim3(256), 0, stream>>>(Wg, xt, xjt, xjct, cbi, outp);
}

// Round 3
// 344.881 us; speedup vs baseline: 1.8155x; 1.1614x over previous
//
#include <hip/hip_runtime.h>
#include <hip/hip_bf16.h>
#include <math.h>

#define B_   4
#define C_   192
#define N_   6400
#define K_   9
#define M_   50
#define TK_  12
#define OC_  192
#define KC_  576     // 3*C
#define CH_  100     // n-chunks for centroid update (64 points each)
#define MS_  25      // m-slice per upd_partial block
#define LSTR 53      // padded lg row stride (fp32; 53 odd -> conflict-free)
#define BSTR 40      // bf16 LDS row stride (80 B, 16B-aligned, 2-way -> free)

typedef __bf16 b16x8 __attribute__((ext_vector_type(8)));
typedef float f32x4 __attribute__((ext_vector_type(4)));

__device__ inline unsigned short f2b(float f) {
    union { __hip_bfloat16 h; unsigned short u; } v;
    v.h = __float2bfloat16(f);
    return v.u;
}

// ---------------- W re-permute -> bf16: Wg16[o][t*192+ch] = conv_w[o][ch*3+t]
__global__ void k_rearrange_w(const float* __restrict__ cw, unsigned short* __restrict__ Wg16) {
    int g = blockIdx.x * 256 + threadIdx.x;           // < 192*576
    int o = g / KC_, r = g % KC_;
    int t = r / C_, ch = r % C_;
    Wg16[g] = f2b(cw[o * KC_ + ch * 3 + t]);
}

// ---------------- transpose x (b,c,n) -> xt fp32 + xt16 bf16 (b,n,c) ---------
__global__ void k_transpose(const float* __restrict__ x, float* __restrict__ xt,
                            unsigned short* __restrict__ xt16) {
    __shared__ float tile[32][33];
    int b = blockIdx.z;
    int p0 = blockIdx.x * 32, c0 = blockIdx.y * 32;
    int tx = threadIdx.x, ty = threadIdx.y;
    const float* xb = x + (size_t)b * C_ * N_;
    float* xtb = xt + (size_t)b * N_ * C_;
    unsigned short* xt16b = xt16 + (size_t)b * N_ * C_;
#pragma unroll
    for (int i = 0; i < 4; i++) {
        int cc = ty + 8 * i;
        tile[cc][tx] = xb[(size_t)(c0 + cc) * N_ + p0 + tx];
    }
    __syncthreads();
#pragma unroll
    for (int i = 0; i < 4; i++) {
        int pp = ty + 8 * i;
        float v = tile[tx][pp];
        size_t o = (size_t)(p0 + pp) * C_ + c0 + tx;
        xtb[o] = v;
        xt16b[o] = f2b(v);
    }
}

// ---------------- initial centroids: 5x10 adaptive avg pool (+ |c|^2) --------
__global__ __launch_bounds__(192) void k_init_cent(const float* __restrict__ xt,
        float* __restrict__ cent, float* __restrict__ c2) {
    int m = blockIdx.x, b = blockIdx.y, c = threadIdx.x;
    int gy = m / 10, gx = m % 10;
    const float* xtb = xt + (size_t)b * N_ * C_;
    float s = 0.f;
    for (int yy = 0; yy < 16; yy++)
        for (int xx = 0; xx < 8; xx++) {
            int p = (gy * 16 + yy) * 80 + gx * 8 + xx;
            s += xtb[(size_t)p * C_ + c];
        }
    float v = s * (1.f / 128.f);
    cent[((size_t)b * M_ + m) * C_ + c] = v;
    float q = v * v;
    __shared__ float red[3];
#pragma unroll
    for (int off = 32; off > 0; off >>= 1) q += __shfl_down(q, off, 64);
    if ((c & 63) == 0) red[c >> 6] = q;
    __syncthreads();
    if (c == 0) c2[(size_t)b * M_ + m] = red[0] + red[1] + red[2];
}

// ---------------- logits GEMM + softmax (+ topk on last iter) ----------------
__global__ __launch_bounds__(256) void k_logits(const float* __restrict__ xt,
        const float* __restrict__ cent, const float* __restrict__ c2g,
        float* __restrict__ w, int* __restrict__ nn, int do_topk) {
    __shared__ float Ac[16][68];
    __shared__ float Bp[16][68];
    __shared__ float lg[64 * LSTR];
    __shared__ float sred[256];
    int b = blockIdx.y;
    int p0 = blockIdx.x * 64;
    int tid = threadIdx.x;
    int tx = tid & 15, ty = tid >> 4;
    int lr = tid >> 2, lq = tid & 3;
    const float* cb = cent + (size_t)b * M_ * C_;
    const float* xb = xt + ((size_t)b * N_ + p0) * C_;
    float acc[4][4];
#pragma unroll
    for (int i = 0; i < 4; i++)
#pragma unroll
        for (int j = 0; j < 4; j++) acc[i][j] = 0.f;
    for (int kt = 0; kt < 12; kt++) {
        int kg = kt * 16;
        float4 cv = make_float4(0.f, 0.f, 0.f, 0.f);
        if (lr < M_) cv = *(const float4*)&cb[(size_t)lr * C_ + kg + 4 * lq];
        float4 pv = *(const float4*)&xb[(size_t)lr * C_ + kg + 4 * lq];
        __syncthreads();
        Ac[4 * lq + 0][lr] = cv.x; Ac[4 * lq + 1][lr] = cv.y;
        Ac[4 * lq + 2][lr] = cv.z; Ac[4 * lq + 3][lr] = cv.w;
        Bp[4 * lq + 0][lr] = pv.x; Bp[4 * lq + 1][lr] = pv.y;
        Bp[4 * lq + 2][lr] = pv.z; Bp[4 * lq + 3][lr] = pv.w;
        __syncthreads();
#pragma unroll
        for (int kk = 0; kk < 16; kk++) {
            float4 a = *(const float4*)&Ac[kk][4 * ty];
            float4 bb = *(const float4*)&Bp[kk][4 * tx];
            acc[0][0] += a.x * bb.x; acc[0][1] += a.x * bb.y; acc[0][2] += a.x * bb.z; acc[0][3] += a.x * bb.w;
            acc[1][0] += a.y * bb.x; acc[1][1] += a.y * bb.y; acc[1][2] += a.y * bb.z; acc[1][3] += a.y * bb.w;
            acc[2][0] += a.z * bb.x; acc[2][1] += a.z * bb.y; acc[2][2] += a.z * bb.z; acc[2][3] += a.z * bb.w;
            acc[3][0] += a.w * bb.x; acc[3][1] += a.w * bb.y; acc[3][2] += a.w * bb.z; acc[3][3] += a.w * bb.w;
        }
    }
    float c2v[4];
#pragma unroll
    for (int i = 0; i < 4; i++) {
        int m = 4 * ty + i;
        c2v[i] = (m < M_) ? c2g[(size_t)b * M_ + m] : 0.f;
    }
#pragma unroll
    for (int i = 0; i < 4; i++) {
        int m = 4 * ty + i;
        if (m < M_) {
#pragma unroll
            for (int j = 0; j < 4; j++)
                lg[(4 * tx + j) * LSTR + m] = 2.f * acc[i][j] - c2v[i];
        }
    }
    __syncthreads();
    // 4-way parallel softmax: thread (p = tid&63, part = tid>>6)
    {
        int p = tid & 63, part = tid >> 6;
        int m0 = part * 13;
        int m1 = (part == 3) ? M_ : m0 + 13;
        float* row = &lg[p * LSTR];
        float mx = -1e30f;
        for (int m = m0; m < m1; m++) mx = fmaxf(mx, row[m]);
        sred[part * 64 + p] = mx;
        __syncthreads();
        mx = fmaxf(fmaxf(sred[p], sred[64 + p]), fmaxf(sred[128 + p], sred[192 + p]));
        float s = 0.f;
        for (int m = m0; m < m1; m++) {
            float e = expf(row[m] - mx);
            row[m] = e;
            s += e;
        }
        __syncthreads();
        sred[part * 64 + p] = s;
        __syncthreads();
        s = sred[p] + sred[64 + p] + sred[128 + p] + sred[192 + p];
        float inv = 1.f / s;
        for (int m = m0; m < m1; m++) row[m] *= inv;
    }
    __syncthreads();
    float* wb = w + ((size_t)b * N_ + p0) * M_;
    for (int j = tid; j < 64 * M_; j += 256) {
        int p = j / M_, m = j - p * M_;
        wb[j] = lg[p * LSTR + m];
    }
    if (do_topk) {
        __syncthreads();
        if (tid < 64) {
            float* row = &lg[tid * LSTR];
            int* nb = nn + ((size_t)b * N_ + p0 + tid) * TK_;
            for (int r = 0; r < TK_; r++) {
                float bv = -1.f;
                int bi = 0;
                for (int m = 0; m < M_; m++) {
                    float v = row[m];
                    if (v > bv) { bv = v; bi = m; }   // strict > : lowest index wins ties
                }
                nb[r] = bi;
                row[bi] = -1.f;
            }
        }
    }
}

// ---------------- centroid update: per-chunk, per-m-slice partial sums -------
__global__ __launch_bounds__(192) void k_upd_partial(const float* __restrict__ xt,
        const float* __restrict__ w, float* __restrict__ part, float* __restrict__ wsp) {
    __shared__ float wl[64 * MS_];
    int ch = blockIdx.x, mh = blockIdx.y, b = blockIdx.z, c = threadIdx.x;
    int m0 = mh * MS_;
    int p0 = ch * 64;
    const float* wb = w + ((size_t)b * N_ + p0) * M_;
    for (int j = c; j < 64 * MS_; j += 192) {
        int p = j / MS_, mm = j - p * MS_;
        wl[j] = wb[p * M_ + m0 + mm];
    }
    __syncthreads();
    float acc[MS_];
#pragma unroll
    for (int mm = 0; mm < MS_; mm++) acc[mm] = 0.f;
    const float* xb = xt + ((size_t)b * N_ + p0) * C_;
    for (int p = 0; p < 64; p++) {
        float xv = xb[(size_t)p * C_ + c];
        const float* wr = &wl[p * MS_];
#pragma unroll
        for (int mm = 0; mm < MS_; mm++) acc[mm] += wr[mm] * xv;
    }
    float* pb = part + (((size_t)b * CH_ + ch) * M_ + m0) * (size_t)C_;
#pragma unroll
    for (int mm = 0; mm < MS_; mm++) pb[(size_t)mm * C_ + c] = acc[mm];
    if (c < MS_) {
        float s = 0.f;
        for (int p = 0; p < 64; p++) s += wl[p * MS_ + c];
        wsp[((size_t)b * CH_ + ch) * M_ + m0 + c] = s;
    }
}

__global__ __launch_bounds__(192) void k_upd_reduce(const float* __restrict__ part,
        const float* __restrict__ wsp, float* __restrict__ cent, float* __restrict__ c2) {
    int m = blockIdx.x, b = blockIdx.y, c = threadIdx.x;
    __shared__ float sws;
    __shared__ float red[3];
    if (c == 0) {
        float s = 0.f;
        for (int ch = 0; ch < CH_; ch++) s += wsp[((size_t)b * CH_ + ch) * M_ + m];
        sws = s + 1e-8f;
    }
    float s = 0.f;
    for (int ch = 0; ch < CH_; ch++)
        s += part[(((size_t)b * CH_ + ch) * M_ + m) * (size_t)C_ + c];
    __syncthreads();
    float v = s / sws;
    cent[((size_t)b * M_ + m) * C_ + c] = v;
    float q = v * v;
#pragma unroll
    for (int off = 32; off > 0; off >>= 1) q += __shfl_down(q, off, 64);
    if ((c & 63) == 0) red[c >> 6] = q;
    __syncthreads();
    if (c == 0) c2[(size_t)b * M_ + m] = red[0] + red[1] + red[2];
}

// ---------------- gathers: edge max-relative + topk-centroid max -> bf16 -----
__global__ __launch_bounds__(192) void k_gather(const float* __restrict__ xt,
        const float* __restrict__ cent, const int* __restrict__ edge,
        const int* __restrict__ nn, unsigned short* __restrict__ xjt16,
        unsigned short* __restrict__ xjct16) {
    __shared__ int sidx[2 * K_ + TK_];
    int p = blockIdx.x, b = blockIdx.y, c = threadIdx.x;
    if (c < K_)
        sidx[c] = edge[((size_t)b * N_ + p) * K_ + c];
    else if (c < 2 * K_)
        sidx[c] = edge[(size_t)B_ * N_ * K_ + ((size_t)b * N_ + p) * K_ + (c - K_)];
    else if (c < 2 * K_ + TK_)
        sidx[c] = nn[((size_t)b * N_ + p) * TK_ + (c - 2 * K_)];
    __syncthreads();
    const float* xb = xt + (size_t)b * N_ * C_;
    const float* cbv = cent + (size_t)b * M_ * C_;
    float xv = xb[(size_t)p * C_ + c];
    float mj = -1e30f;
#pragma unroll
    for (int kk = 0; kk < K_; kk++) {
        float vj = xb[(size_t)sidx[kk] * C_ + c];
        float vi = xb[(size_t)sidx[K_ + kk] * C_ + c];
        mj = fmaxf(mj, vj - vi);
    }
    float mc = -1e30f;
#pragma unroll
    for (int kk = 0; kk < TK_; kk++)
        mc = fmaxf(mc, cbv[(size_t)sidx[2 * K_ + kk] * C_ + c]);
    size_t o = ((size_t)b * N_ + p) * C_ + c;
    xjt16[o] = f2b(mj);
    xjct16[o] = f2b(mc - xv);
}

// ---------------- final conv via bf16 MFMA: 64(o) x 128(p) tile --------------
__global__ __launch_bounds__(256) void k_gemm(const unsigned short* __restrict__ Wg16,
        const unsigned short* __restrict__ xt16, const unsigned short* __restrict__ xjt16,
        const unsigned short* __restrict__ xjct16, const float* __restrict__ bias,
        float* __restrict__ out) {
    __shared__ short As[64 * BSTR];    // Wg tile [o][k], padded rows
    __shared__ short Bs[128 * BSTR];   // feat tile [p][k], padded rows
    int b = blockIdx.z;
    int po = blockIdx.x * 128, oo = blockIdx.y * 64;
    int tid = threadIdx.x;
    int wave = tid >> 6, lane = tid & 63;
    int m16 = lane & 15, q = lane >> 4;
    const unsigned short* s0 = xt16 + (size_t)b * N_ * C_;
    const unsigned short* s1 = xjt16 + (size_t)b * N_ * C_;
    const unsigned short* s2 = xjct16 + (size_t)b * N_ * C_;
    f32x4 acc[4][2];
#pragma unroll
    for (int i = 0; i < 4; i++)
#pragma unroll
        for (int j = 0; j < 2; j++) acc[i][j] = (f32x4){0.f, 0.f, 0.f, 0.f};
    int arow = tid >> 2, ach = tid & 3;                 // A: 64 rows x 4 chunks
    int brow0 = tid >> 1, bch0 = (tid & 1) * 2;         // B: 128 rows x 4 chunks; 2/thread
    for (int kt = 0; kt < 18; kt++) {
        int kg = kt * 32;
        int prt = kg / C_, koff = kg - prt * C_;
        const unsigned short* src = (prt == 0) ? s0 : ((prt == 1) ? s1 : s2);
        int4 av = *(const int4*)&Wg16[(size_t)(oo + arow) * KC_ + kg + ach * 8];
        int4 bv0 = *(const int4*)&src[(size_t)(po + brow0) * C_ + koff + bch0 * 8];
        int4 bv1 = *(const int4*)&src[(size_t)(po + brow0) * C_ + koff + bch0 * 8 + 8];
        __syncthreads();
        *(int4*)&As[arow * BSTR + ach * 8] = av;
        *(int4*)&Bs[brow0 * BSTR + bch0 * 8] = bv0;
        *(int4*)&Bs[brow0 * BSTR + bch0 * 8 + 8] = bv1;
        __syncthreads();
        b16x8 af[4], bf[2];
#pragma unroll
        for (int of = 0; of < 4; of++)
            af[of] = *(const b16x8*)&As[(of * 16 + m16) * BSTR + q * 8];
#pragma unroll
        for (int pf = 0; pf < 2; pf++)
            bf[pf] = *(const b16x8*)&Bs[(wave * 32 + pf * 16 + m16) * BSTR + q * 8];
#pragma unroll
        for (int of = 0; of < 4; of++)
#pragma unroll
            for (int pf = 0; pf < 2; pf++)
                acc[of][pf] = __builtin_amdgcn_mfma_f32_16x16x32_bf16(af[of], bf[pf], acc[of][pf], 0, 0, 0);
    }
    // epilogue: D row = q*4+reg (o), col = m16 (p)
#pragma unroll
    for (int of = 0; of < 4; of++) {
        float4 bv = *(const float4*)&bias[oo + of * 16 + q * 4];
        float bia[4] = {bv.x, bv.y, bv.z, bv.w};
#pragma unroll
        for (int pf = 0; pf < 2; pf++) {
            int p = po + wave * 32 + pf * 16 + m16;
#pragma unroll
            for (int r = 0; r < 4; r++) {
                int o = oo + of * 16 + q * 4 + r;
                out[((size_t)b * OC_ + o) * N_ + p] = fmaxf(acc[of][pf][r] + bia[r], 0.f);
            }
        }
    }
}

extern "C" void kernel_launch(void* const* d_in, const int* in_sizes, int n_in,
                              void* d_out, int out_size, void* d_ws, size_t ws_size,
                              hipStream_t stream) {
    (void)in_sizes; (void)n_in; (void)out_size; (void)ws_size;
    const float* x   = (const float*)d_in[0];
    const int* edge  = (const int*)d_in[1];
    const float* cw  = (const float*)d_in[2];
    const float* cbi = (const float*)d_in[3];
    float* ws = (float*)d_ws;
    size_t o = 0;
    float* xt   = ws + o; o += (size_t)B_ * N_ * C_;             // fp32
    unsigned short* xt16 = (unsigned short*)(ws + o); o += (size_t)B_ * N_ * C_ / 2;
    unsigned short* Wg16 = (unsigned short*)(ws + o); o += (size_t)OC_ * KC_ / 2;
    float* cent = ws + o; o += (size_t)B_ * M_ * C_;
    float* c2   = ws + o; o += (size_t)B_ * M_;
    float* w    = ws + o; o += (size_t)B_ * N_ * M_;
    float* part = ws + o; o += (size_t)B_ * CH_ * M_ * C_;
    float* wsp  = ws + o; o += (size_t)B_ * CH_ * M_;
    int* nn = (int*)(ws + o); o += (size_t)B_ * N_ * TK_;
    unsigned short* xjt16  = (unsigned short*)(ws + o); o += (size_t)B_ * N_ * C_ / 2;
    unsigned short* xjct16 = (unsigned short*)(ws + o); o += (size_t)B_ * N_ * C_ / 2;
    float* outp = (float*)d_out;

    k_rearrange_w<<<dim3(432), dim3(256), 0, stream>>>(cw, Wg16);
    k_transpose<<<dim3(N_ / 32, C_ / 32, B_), dim3(32, 8), 0, stream>>>(x, xt, xt16);
    k_init_cent<<<dim3(M_, B_), dim3(192), 0, stream>>>(xt, cent, c2);
    for (int it = 0; it < 3; it++) {
        k_logits<<<dim3(N_ / 64, B_), dim3(256), 0, stream>>>(xt, cent, c2, w, nn, (it == 2) ? 1 : 0);
        k_upd_partial<<<dim3(CH_, 2, B_), dim3(192), 0, stream>>>(xt, w, part, wsp);
        k_upd_reduce<<<dim3(M_, B_), dim3(192), 0, stream>>>(part, wsp, cent, c2);
    }
    k_gather<<<dim3(N_, B_), dim3(192), 0, stream>>>(xt, cent, edge, nn, xjt16, xjct16);
    k_gemm<<<dim3(N_ / 128, OC_ / 64, B_), dim3(256), 0, stream>>>(Wg16, xt16, xjt16, xjct16, cbi, outp);
}